// Round 10
// baseline (163.703 us; speedup 1.0000x reference)
//
#include <hip/hip_runtime.h>

#define B_  4
#define S_  4096
#define DM  1024
#define DK  64
#define NSPLIT 16
#define KSPAN (S_ / NSPLIT)
#define QT  256                  // queries per flash block

typedef _Float16 half8  __attribute__((ext_vector_type(8)));
typedef _Float16 half4v __attribute__((ext_vector_type(4)));
typedef __fp16   fp16x2 __attribute__((ext_vector_type(2)));   // cvt_pkrtz return type
typedef float    floatx4 __attribute__((ext_vector_type(4)));

// 0.125 (1/sqrt(64)) * log2(e): softmax in exp2 domain
#define QSCALE 0.18033688011112042f
#define EXP2F(x) __builtin_amdgcn_exp2f(x)

// ---------------------------------------------------------------------------
// One-time W transpose+convert: Wt[proj][n][k] f16  <-  W[k][n] fp32.
// ---------------------------------------------------------------------------
__global__ __launch_bounds__(256) void wt_kernel(
    const float* __restrict__ WQ, const float* __restrict__ WK,
    const float* __restrict__ WV, _Float16* __restrict__ Wt)
{
    const int proj = blockIdx.y;
    const float* W = (proj == 0) ? WQ : (proj == 1) ? WK : WV;
    const int k0 = blockIdx.x * 64;
    const int t = threadIdx.x;
    __shared__ float T[64][68];

    #pragma unroll
    for (int p = 0; p < 4; p++) {
        int c = p * 256 + t;
        int k = c >> 4, n4 = (c & 15) * 4;
        float4 v = *(const float4*)(W + (size_t)(k0 + k) * DK + n4);
        T[k][n4 + 0] = v.x; T[k][n4 + 1] = v.y;
        T[k][n4 + 2] = v.z; T[k][n4 + 3] = v.w;
    }
    __syncthreads();

    const int n = t >> 2, kc = (t & 3) * 16;
    half8 h0, h1;
    #pragma unroll
    for (int j = 0; j < 8; j++) h0[j] = (_Float16)T[kc + j][n];
    #pragma unroll
    for (int j = 0; j < 8; j++) h1[j] = (_Float16)T[kc + 8 + j][n];
    _Float16* dst = Wt + ((size_t)proj * 64 + n) * DM + k0 + kc;
    *(half8*)(dst)     = h0;
    *(half8*)(dst + 8) = h1;
}

// ---------------------------------------------------------------------------
// Proj v6 (unchanged from R9): N-split-2, fat-wave pipeline, 2 blocks/CU.
// ---------------------------------------------------------------------------
__global__ __launch_bounds__(256) void proj_mfma_kernel(
    const float* __restrict__ X, const _Float16* __restrict__ Wt,
    const float* __restrict__ bQ, const float* __restrict__ bK,
    const float* __restrict__ bV,
    _Float16* __restrict__ Qh, _Float16* __restrict__ Kh,
    _Float16* __restrict__ Vt)
{
    const int r0   = blockIdx.x * 64;
    const int nh   = blockIdx.y;          // N-half: cols nh*96 .. nh*96+95
    const int t    = threadIdx.x;
    const int wave = t >> 6, lane = t & 63;
    const int quad = lane >> 4, l15 = lane & 15;

    __shared__ __align__(16) _Float16 Xs[64 * 72];        //  9 KB
    __shared__ __align__(16) _Float16 Ws[96 * 72];        // 13.5 KB

    const _Float16* Wb = Wt + (size_t)(nh * 96) * DM;

    floatx4 acc[6];
    #pragma unroll
    for (int j = 0; j < 6; j++) acc[j] = (floatx4){0.f, 0.f, 0.f, 0.f};

    int xrow[4], xcol[4];
    #pragma unroll
    for (int p = 0; p < 4; p++) {
        int c = p * 256 + t;
        xrow[p] = c >> 4; xcol[p] = (c & 15) * 4;
    }
    int wrow[3], wcol[3];                  // 96 rows x 64 cols = 3 half8/thread
    #pragma unroll
    for (int p = 0; p < 3; p++) {
        int c = p * 256 + t;
        wrow[p] = c >> 3; wcol[p] = (c & 7) * 8;
    }

    float4 xr[4]; half8 wr[3];
    #pragma unroll
    for (int p = 0; p < 4; p++)
        xr[p] = *(const float4*)(X + (size_t)(r0 + xrow[p]) * DM + xcol[p]);
    #pragma unroll
    for (int p = 0; p < 3; p++)
        wr[p] = *(const half8*)(Wb + (size_t)wrow[p] * DM + wcol[p]);

    for (int kt = 0; kt < DM / 64; kt++) {
        __syncthreads();
        #pragma unroll
        for (int p = 0; p < 4; p++) {
            half4v h;
            h[0] = (_Float16)xr[p].x; h[1] = (_Float16)xr[p].y;
            h[2] = (_Float16)xr[p].z; h[3] = (_Float16)xr[p].w;
            *(half4v*)&Xs[xrow[p] * 72 + xcol[p]] = h;
        }
        #pragma unroll
        for (int p = 0; p < 3; p++)
            *(half8*)&Ws[wrow[p] * 72 + wcol[p]] = wr[p];
        __syncthreads();

        if (kt + 1 < DM / 64) {
            const int kn = (kt + 1) * 64;
            #pragma unroll
            for (int p = 0; p < 4; p++)
                xr[p] = *(const float4*)(X + (size_t)(r0 + xrow[p]) * DM + kn + xcol[p]);
            #pragma unroll
            for (int p = 0; p < 3; p++)
                wr[p] = *(const half8*)(Wb + (size_t)wrow[p] * DM + kn + wcol[p]);
        }

        half8 xa0 = *(half8*)&Xs[(wave * 16 + l15) * 72 + quad * 8];
        half8 xa1 = *(half8*)&Xs[(wave * 16 + l15) * 72 + 32 + quad * 8];
        #pragma unroll
        for (int j = 0; j < 6; j++) {
            half8 bf0 = *(half8*)&Ws[(j * 16 + l15) * 72 + quad * 8];
            half8 bf1 = *(half8*)&Ws[(j * 16 + l15) * 72 + 32 + quad * 8];
            floatx4 a = acc[j];
            a = __builtin_amdgcn_mfma_f32_16x16x32_f16(xa0, bf0, a, 0, 0, 0);
            a = __builtin_amdgcn_mfma_f32_16x16x32_f16(xa1, bf1, a, 0, 0, 0);
            acc[j] = a;
        }
    }

    // epilogue: flat tile fg = nh*6+j in 0..11 -> proj = fg>>2, d-tile = fg&3
    const int orow = r0 + wave * 16 + quad * 4;
    const int bidx = r0 >> 12;
    const int s0   = (r0 & (S_ - 1)) + wave * 16 + quad * 4;

    if (nh == 0) {
        #pragma unroll
        for (int j = 0; j < 4; j++) {
            const int d = j * 16 + l15;
            const float bq = bQ[d];
            #pragma unroll
            for (int i = 0; i < 4; i++)
                Qh[(size_t)(orow + i) * DK + d] =
                    (_Float16)((acc[j][i] + bq) * QSCALE);
        }
        #pragma unroll
        for (int j = 4; j < 6; j++) {
            const int d = (j - 4) * 16 + l15;
            const float bk = bK[d];
            #pragma unroll
            for (int i = 0; i < 4; i++)
                Kh[(size_t)(orow + i) * DK + d] =
                    (_Float16)(acc[j][i] + bk);
        }
    } else {
        #pragma unroll
        for (int j = 0; j < 2; j++) {
            const int d = (2 + j) * 16 + l15;
            const float bk = bK[d];
            #pragma unroll
            for (int i = 0; i < 4; i++)
                Kh[(size_t)(orow + i) * DK + d] =
                    (_Float16)(acc[j][i] + bk);
        }
        #pragma unroll
        for (int j = 2; j < 6; j++) {
            const int d = (j - 2) * 16 + l15;
            const float bv = bV[d];
            half4v hv;
            #pragma unroll
            for (int i = 0; i < 4; i++)
                hv[i] = (_Float16)(acc[j][i] + bv);
            *(half4v*)(Vt + (size_t)bidx * DK * S_ + (size_t)d * S_ + s0) = hv;
        }
    }
}

// ---------------------------------------------------------------------------
// Flash v7 (code unchanged from R9). NSPLIT 16 -> grid 1024 = 4 blocks/CU
// (LDS 36 KB, VGPR<=128 both permit 4): 32 waves/CU, full MFMA+VALU
// co-schedule across independent blocks (m114 regime).
// ---------------------------------------------------------------------------
__global__ __launch_bounds__(512, 4) void flash_mfma_kernel(
    const _Float16* __restrict__ Qh, const _Float16* __restrict__ Kh,
    const _Float16* __restrict__ Vt, _Float16* __restrict__ Oph,
    float* __restrict__ Lp)
{
    const int b     = blockIdx.y;
    const int q0    = blockIdx.x * QT;
    const int split = blockIdx.z;
    const int kbase = split * KSPAN;
    const int t     = threadIdx.x;
    const int wave  = t >> 6, lane = t & 63;
    const int quad  = lane >> 4, l15 = lane & 15;

    __shared__ __align__(16) _Float16 Ks[2][64 * 72];     // key-permuted rows
    __shared__ __align__(16) _Float16 Vs[2][64 * 72];     // [d][key]

    const _Float16* Qb = Qh + ((size_t)b * S_ + q0) * DK;
    const _Float16* Kb = Kh + ((size_t)b * S_ + kbase) * DK;
    const _Float16* Vb = Vt + (size_t)b * DK * S_ + kbase;

    half8 qf0[2], qf1[2];
    #pragma unroll
    for (int mt = 0; mt < 2; mt++) {
        const _Float16* qr = Qb + (size_t)(wave * 32 + mt * 16 + l15) * DK;
        qf0[mt] = *(const half8*)(qr + quad * 8);
        qf1[mt] = *(const half8*)(qr + 32 + quad * 8);
    }

    floatx4 acc[2][4];
    float rs[2];
    #pragma unroll
    for (int mt = 0; mt < 2; mt++) {
        #pragma unroll
        for (int nt = 0; nt < 4; nt++) acc[mt][nt] = (floatx4){0.f,0.f,0.f,0.f};
        rs[mt] = 0.f;
    }

    const int kr   = t >> 3, kcol = (t & 7) * 8;
    const int krP  = (kr & 32) | ((kr & 4) << 2) | ((kr & 24) >> 1) | (kr & 3);
    half8 kreg = *(const half8*)(Kb + (size_t)kr * DK + kcol);
    half8 vreg = *(const half8*)(Vb + (size_t)kr * S_ + kcol);
    *(half8*)&Ks[0][krP * 72 + kcol] = kreg;
    *(half8*)&Vs[0][kr  * 72 + kcol] = vreg;

    const int NT = KSPAN / 64;
    int cur = 0;
    for (int it = 0; it < NT; it++) {
        __syncthreads();     // buf[cur] ready; everyone done with buf[cur^1]

        if (it + 1 < NT) {
            const int kn = (it + 1) * 64;
            kreg = *(const half8*)(Kb + (size_t)(kn + kr) * DK + kcol);
            vreg = *(const half8*)(Vb + (size_t)kr * S_ + kn + kcol);
        }

        // QK^T fused with softmax numerator: each z consumed immediately
        half8 pf0[2], pf1[2];
        __builtin_amdgcn_s_setprio(1);
        #pragma unroll
        for (int nt = 0; nt < 4; nt++) {
            half8 kf0 = *(half8*)&Ks[cur][(nt * 16 + l15) * 72 + quad * 8];
            half8 kf1 = *(half8*)&Ks[cur][(nt * 16 + l15) * 72 + 32 + quad * 8];
            #pragma unroll
            for (int mt = 0; mt < 2; mt++) {
                floatx4 z = (floatx4){0.f, 0.f, 0.f, 0.f};
                z = __builtin_amdgcn_mfma_f32_16x16x32_f16(kf0, qf0[mt], z, 0, 0, 0);
                z = __builtin_amdgcn_mfma_f32_16x16x32_f16(kf1, qf1[mt], z, 0, 0, 0);
                float p0 = EXP2F(z[0]), p1 = EXP2F(z[1]);
                float p2 = EXP2F(z[2]), p3 = EXP2F(z[3]);
                rs[mt] += p0; rs[mt] += p1; rs[mt] += p2; rs[mt] += p3;
                fp16x2 ca = __builtin_amdgcn_cvt_pkrtz(p0, p1);
                fp16x2 cb = __builtin_amdgcn_cvt_pkrtz(p2, p3);
                if (nt < 2) {
                    pf0[mt][(nt & 1) * 4 + 0] = (_Float16)ca[0];
                    pf0[mt][(nt & 1) * 4 + 1] = (_Float16)ca[1];
                    pf0[mt][(nt & 1) * 4 + 2] = (_Float16)cb[0];
                    pf0[mt][(nt & 1) * 4 + 3] = (_Float16)cb[1];
                } else {
                    pf1[mt][(nt & 1) * 4 + 0] = (_Float16)ca[0];
                    pf1[mt][(nt & 1) * 4 + 1] = (_Float16)ca[1];
                    pf1[mt][(nt & 1) * 4 + 2] = (_Float16)cb[0];
                    pf1[mt][(nt & 1) * 4 + 3] = (_Float16)cb[1];
                }
            }
        }
        __builtin_amdgcn_s_setprio(0);

        // O^T += V^T·P^T
        __builtin_amdgcn_s_setprio(1);
        #pragma unroll
        for (int nt = 0; nt < 4; nt++) {
            half8 vf0 = *(half8*)&Vs[cur][(nt * 16 + l15) * 72 + quad * 8];
            half8 vf1 = *(half8*)&Vs[cur][(nt * 16 + l15) * 72 + 32 + quad * 8];
            #pragma unroll
            for (int mt = 0; mt < 2; mt++) {
                floatx4 a = acc[mt][nt];
                a = __builtin_amdgcn_mfma_f32_16x16x32_f16(vf0, pf0[mt], a, 0, 0, 0);
                a = __builtin_amdgcn_mfma_f32_16x16x32_f16(vf1, pf1[mt], a, 0, 0, 0);
                acc[mt][nt] = a;
            }
        }
        __builtin_amdgcn_s_setprio(0);

        if (it + 1 < NT) {
            *(half8*)&Ks[cur ^ 1][krP * 72 + kcol] = kreg;
            *(half8*)&Vs[cur ^ 1][kr  * 72 + kcol] = vreg;
        }
        cur ^= 1;
    }

    const size_t prow = (size_t)split * B_ * S_ + (size_t)b * S_ + q0;
    #pragma unroll
    for (int mt = 0; mt < 2; mt++) {
        float r = rs[mt];
        r += __shfl_xor(r, 16, 64);
        r += __shfl_xor(r, 32, 64);
        const float inv = 1.0f / r;
        const size_t orow = prow + wave * 32 + mt * 16 + l15;
        #pragma unroll
        for (int nt = 0; nt < 4; nt++) {
            half4v hv;
            #pragma unroll
            for (int i = 0; i < 4; i++)
                hv[i] = (_Float16)(acc[mt][nt][i] * inv);
            *(half4v*)(Oph + orow * DK + nt * 16 + quad * 4) = hv;
        }
        if (quad == 0)
            Lp[orow] = r;
    }
}

// ---------------------------------------------------------------------------
// Combine: O[r] = sum_s l_s * Ohat_s[r] / sum_s l_s.  16 rows x 16 lanes.
// ---------------------------------------------------------------------------
__global__ __launch_bounds__(256) void combine_kernel(
    const _Float16* __restrict__ Oph, const float* __restrict__ Lp,
    float* __restrict__ O)
{
    const int r  = blockIdx.x * 16 + (threadIdx.x >> 4);
    const int d4 = (threadIdx.x & 15) * 4;
    const int NR = B_ * S_;

    float lw[NSPLIT], lsum = 0.f;
    #pragma unroll
    for (int s = 0; s < NSPLIT; s++) {
        lw[s] = Lp[(size_t)s * NR + r];
        lsum += lw[s];
    }
    const float inv = 1.0f / lsum;

    float o[4] = {0.f, 0.f, 0.f, 0.f};
    #pragma unroll
    for (int s = 0; s < NSPLIT; s++) {
        half4v h = *(const half4v*)(Oph + ((size_t)s * NR + r) * DK + d4);
        const float w = lw[s];
        #pragma unroll
        for (int j = 0; j < 4; j++) o[j] += w * (float)h[j];
    }
    float4 out;
    out.x = o[0] * inv; out.y = o[1] * inv;
    out.z = o[2] * inv; out.w = o[3] * inv;
    *(float4*)(O + (size_t)r * DK + d4) = out;
}

// ---------------------------------------------------------------------------
extern "C" void kernel_launch(void* const* d_in, const int* in_sizes, int n_in,
                              void* d_out, int out_size, void* d_ws, size_t ws_size,
                              hipStream_t stream)
{
    const float* X  = (const float*)d_in[0];
    // cultural path (d_in[1], d_in[8..10]) cancels in softmax -> unused
    const float* WQ = (const float*)d_in[2];
    const float* bQ = (const float*)d_in[3];
    const float* WK = (const float*)d_in[4];
    const float* bK = (const float*)d_in[5];
    const float* WV = (const float*)d_in[6];
    const float* bV = (const float*)d_in[7];

    char* ws = (char*)d_ws;
    _Float16* Qh  = (_Float16*)ws;  ws += (size_t)B_ * S_ * DK * 2;   // 2 MiB
    _Float16* Kh  = (_Float16*)ws;  ws += (size_t)B_ * S_ * DK * 2;
    _Float16* Vt  = (_Float16*)ws;  ws += (size_t)B_ * S_ * DK * 2;
    _Float16* Wt  = (_Float16*)ws;  ws += (size_t)3 * 64 * DM * 2;    // 384 KiB
    _Float16* Oph = (_Float16*)ws;  ws += (size_t)NSPLIT * B_ * S_ * DK * 2; // 32 MiB
    float* Lp     = (float*)ws;

    wt_kernel<<<dim3(DM / 64, 3), 256, 0, stream>>>(WQ, WK, WV, Wt);

    proj_mfma_kernel<<<dim3((B_ * S_) / 64, 2), 256, 0, stream>>>(
        X, Wt, bQ, bK, bV, Qh, Kh, Vt);

    flash_mfma_kernel<<<dim3(S_ / QT, B_, NSPLIT), 512, 0, stream>>>(
        Qh, Kh, Vt, Oph, Lp);

    combine_kernel<<<dim3((B_ * S_) / 16), 256, 0, stream>>>(
        Oph, Lp, (float*)d_out);
}

// Round 11
// 153.125 us; speedup vs baseline: 1.0691x; 1.0691x over previous
//
#include <hip/hip_runtime.h>

#define B_  4
#define S_  4096
#define DM  1024
#define DK  64
#define NSPLIT 8
#define KSPAN (S_ / NSPLIT)
#define QT  256                  // queries per flash block

typedef _Float16 half8  __attribute__((ext_vector_type(8)));
typedef _Float16 half4v __attribute__((ext_vector_type(4)));
typedef __fp16   fp16x2 __attribute__((ext_vector_type(2)));   // cvt_pkrtz return type
typedef float    floatx4 __attribute__((ext_vector_type(4)));

// 0.125 (1/sqrt(64)) * log2(e): softmax in exp2 domain
#define QSCALE 0.18033688011112042f
#define EXP2F(x) __builtin_amdgcn_exp2f(x)

// ---------------------------------------------------------------------------
// One-time W transpose+convert: Wt[proj][n][k] f16  <-  W[k][n] fp32.
// ---------------------------------------------------------------------------
__global__ __launch_bounds__(256) void wt_kernel(
    const float* __restrict__ WQ, const float* __restrict__ WK,
    const float* __restrict__ WV, _Float16* __restrict__ Wt)
{
    const int proj = blockIdx.y;
    const float* W = (proj == 0) ? WQ : (proj == 1) ? WK : WV;
    const int k0 = blockIdx.x * 64;
    const int t = threadIdx.x;
    __shared__ float T[64][68];

    #pragma unroll
    for (int p = 0; p < 4; p++) {
        int c = p * 256 + t;
        int k = c >> 4, n4 = (c & 15) * 4;
        float4 v = *(const float4*)(W + (size_t)(k0 + k) * DK + n4);
        T[k][n4 + 0] = v.x; T[k][n4 + 1] = v.y;
        T[k][n4 + 2] = v.z; T[k][n4 + 3] = v.w;
    }
    __syncthreads();

    const int n = t >> 2, kc = (t & 3) * 16;
    half8 h0, h1;
    #pragma unroll
    for (int j = 0; j < 8; j++) h0[j] = (_Float16)T[kc + j][n];
    #pragma unroll
    for (int j = 0; j < 8; j++) h1[j] = (_Float16)T[kc + 8 + j][n];
    _Float16* dst = Wt + ((size_t)proj * 64 + n) * DM + k0 + kc;
    *(half8*)(dst)     = h0;
    *(half8*)(dst + 8) = h1;
}

// ---------------------------------------------------------------------------
// Proj v6 (best measured): N-split-2, fat-wave pipeline, 2 blocks/CU.
// ---------------------------------------------------------------------------
__global__ __launch_bounds__(256) void proj_mfma_kernel(
    const float* __restrict__ X, const _Float16* __restrict__ Wt,
    const float* __restrict__ bQ, const float* __restrict__ bK,
    const float* __restrict__ bV,
    _Float16* __restrict__ Qh, _Float16* __restrict__ Kh,
    _Float16* __restrict__ Vt)
{
    const int r0   = blockIdx.x * 64;
    const int nh   = blockIdx.y;          // N-half: cols nh*96 .. nh*96+95
    const int t    = threadIdx.x;
    const int wave = t >> 6, lane = t & 63;
    const int quad = lane >> 4, l15 = lane & 15;

    __shared__ __align__(16) _Float16 Xs[64 * 72];        //  9 KB
    __shared__ __align__(16) _Float16 Ws[96 * 72];        // 13.5 KB

    const _Float16* Wb = Wt + (size_t)(nh * 96) * DM;

    floatx4 acc[6];
    #pragma unroll
    for (int j = 0; j < 6; j++) acc[j] = (floatx4){0.f, 0.f, 0.f, 0.f};

    int xrow[4], xcol[4];
    #pragma unroll
    for (int p = 0; p < 4; p++) {
        int c = p * 256 + t;
        xrow[p] = c >> 4; xcol[p] = (c & 15) * 4;
    }
    int wrow[3], wcol[3];                  // 96 rows x 64 cols = 3 half8/thread
    #pragma unroll
    for (int p = 0; p < 3; p++) {
        int c = p * 256 + t;
        wrow[p] = c >> 3; wcol[p] = (c & 7) * 8;
    }

    float4 xr[4]; half8 wr[3];
    #pragma unroll
    for (int p = 0; p < 4; p++)
        xr[p] = *(const float4*)(X + (size_t)(r0 + xrow[p]) * DM + xcol[p]);
    #pragma unroll
    for (int p = 0; p < 3; p++)
        wr[p] = *(const half8*)(Wb + (size_t)wrow[p] * DM + wcol[p]);

    for (int kt = 0; kt < DM / 64; kt++) {
        __syncthreads();
        #pragma unroll
        for (int p = 0; p < 4; p++) {
            half4v h;
            h[0] = (_Float16)xr[p].x; h[1] = (_Float16)xr[p].y;
            h[2] = (_Float16)xr[p].z; h[3] = (_Float16)xr[p].w;
            *(half4v*)&Xs[xrow[p] * 72 + xcol[p]] = h;
        }
        #pragma unroll
        for (int p = 0; p < 3; p++)
            *(half8*)&Ws[wrow[p] * 72 + wcol[p]] = wr[p];
        __syncthreads();

        if (kt + 1 < DM / 64) {
            const int kn = (kt + 1) * 64;
            #pragma unroll
            for (int p = 0; p < 4; p++)
                xr[p] = *(const float4*)(X + (size_t)(r0 + xrow[p]) * DM + kn + xcol[p]);
            #pragma unroll
            for (int p = 0; p < 3; p++)
                wr[p] = *(const half8*)(Wb + (size_t)wrow[p] * DM + kn + wcol[p]);
        }

        half8 xa0 = *(half8*)&Xs[(wave * 16 + l15) * 72 + quad * 8];
        half8 xa1 = *(half8*)&Xs[(wave * 16 + l15) * 72 + 32 + quad * 8];
        #pragma unroll
        for (int j = 0; j < 6; j++) {
            half8 bf0 = *(half8*)&Ws[(j * 16 + l15) * 72 + quad * 8];
            half8 bf1 = *(half8*)&Ws[(j * 16 + l15) * 72 + 32 + quad * 8];
            floatx4 a = acc[j];
            a = __builtin_amdgcn_mfma_f32_16x16x32_f16(xa0, bf0, a, 0, 0, 0);
            a = __builtin_amdgcn_mfma_f32_16x16x32_f16(xa1, bf1, a, 0, 0, 0);
            acc[j] = a;
        }
    }

    // epilogue: flat tile fg = nh*6+j in 0..11 -> proj = fg>>2, d-tile = fg&3
    const int orow = r0 + wave * 16 + quad * 4;
    const int bidx = r0 >> 12;
    const int s0   = (r0 & (S_ - 1)) + wave * 16 + quad * 4;

    if (nh == 0) {
        #pragma unroll
        for (int j = 0; j < 4; j++) {
            const int d = j * 16 + l15;
            const float bq = bQ[d];
            #pragma unroll
            for (int i = 0; i < 4; i++)
                Qh[(size_t)(orow + i) * DK + d] =
                    (_Float16)((acc[j][i] + bq) * QSCALE);
        }
        #pragma unroll
        for (int j = 4; j < 6; j++) {
            const int d = (j - 4) * 16 + l15;
            const float bk = bK[d];
            #pragma unroll
            for (int i = 0; i < 4; i++)
                Kh[(size_t)(orow + i) * DK + d] =
                    (_Float16)(acc[j][i] + bk);
        }
    } else {
        #pragma unroll
        for (int j = 0; j < 2; j++) {
            const int d = (2 + j) * 16 + l15;
            const float bk = bK[d];
            #pragma unroll
            for (int i = 0; i < 4; i++)
                Kh[(size_t)(orow + i) * DK + d] =
                    (_Float16)(acc[j][i] + bk);
        }
        #pragma unroll
        for (int j = 2; j < 6; j++) {
            const int d = (j - 2) * 16 + l15;
            const float bv = bV[d];
            half4v hv;
            #pragma unroll
            for (int i = 0; i < 4; i++)
                hv[i] = (_Float16)(acc[j][i] + bv);
            *(half4v*)(Vt + (size_t)bidx * DK * S_ + (size_t)d * S_ + s0) = hv;
        }
    }
}

// ---------------------------------------------------------------------------
// Flash v7 (best measured): swapped-operand MFMA, key-permuted K staging,
// fused in-register softmax, setprio around MFMA clusters, 2 blocks/CU.
// ---------------------------------------------------------------------------
__global__ __launch_bounds__(512, 4) void flash_mfma_kernel(
    const _Float16* __restrict__ Qh, const _Float16* __restrict__ Kh,
    const _Float16* __restrict__ Vt, _Float16* __restrict__ Oph,
    float* __restrict__ Lp)
{
    const int b     = blockIdx.y;
    const int q0    = blockIdx.x * QT;
    const int split = blockIdx.z;
    const int kbase = split * KSPAN;
    const int t     = threadIdx.x;
    const int wave  = t >> 6, lane = t & 63;
    const int quad  = lane >> 4, l15 = lane & 15;

    __shared__ __align__(16) _Float16 Ks[2][64 * 72];     // key-permuted rows
    __shared__ __align__(16) _Float16 Vs[2][64 * 72];     // [d][key]

    const _Float16* Qb = Qh + ((size_t)b * S_ + q0) * DK;
    const _Float16* Kb = Kh + ((size_t)b * S_ + kbase) * DK;
    const _Float16* Vb = Vt + (size_t)b * DK * S_ + kbase;

    half8 qf0[2], qf1[2];
    #pragma unroll
    for (int mt = 0; mt < 2; mt++) {
        const _Float16* qr = Qb + (size_t)(wave * 32 + mt * 16 + l15) * DK;
        qf0[mt] = *(const half8*)(qr + quad * 8);
        qf1[mt] = *(const half8*)(qr + 32 + quad * 8);
    }

    floatx4 acc[2][4];
    float rs[2];
    #pragma unroll
    for (int mt = 0; mt < 2; mt++) {
        #pragma unroll
        for (int nt = 0; nt < 4; nt++) acc[mt][nt] = (floatx4){0.f,0.f,0.f,0.f};
        rs[mt] = 0.f;
    }

    const int kr   = t >> 3, kcol = (t & 7) * 8;
    const int krP  = (kr & 32) | ((kr & 4) << 2) | ((kr & 24) >> 1) | (kr & 3);
    half8 kreg = *(const half8*)(Kb + (size_t)kr * DK + kcol);
    half8 vreg = *(const half8*)(Vb + (size_t)kr * S_ + kcol);
    *(half8*)&Ks[0][krP * 72 + kcol] = kreg;
    *(half8*)&Vs[0][kr  * 72 + kcol] = vreg;

    const int NT = KSPAN / 64;
    int cur = 0;
    for (int it = 0; it < NT; it++) {
        __syncthreads();     // buf[cur] ready; everyone done with buf[cur^1]

        if (it + 1 < NT) {
            const int kn = (it + 1) * 64;
            kreg = *(const half8*)(Kb + (size_t)(kn + kr) * DK + kcol);
            vreg = *(const half8*)(Vb + (size_t)kr * S_ + kn + kcol);
        }

        // QK^T fused with softmax numerator: each z consumed immediately
        half8 pf0[2], pf1[2];
        __builtin_amdgcn_s_setprio(1);
        #pragma unroll
        for (int nt = 0; nt < 4; nt++) {
            half8 kf0 = *(half8*)&Ks[cur][(nt * 16 + l15) * 72 + quad * 8];
            half8 kf1 = *(half8*)&Ks[cur][(nt * 16 + l15) * 72 + 32 + quad * 8];
            #pragma unroll
            for (int mt = 0; mt < 2; mt++) {
                floatx4 z = (floatx4){0.f, 0.f, 0.f, 0.f};
                z = __builtin_amdgcn_mfma_f32_16x16x32_f16(kf0, qf0[mt], z, 0, 0, 0);
                z = __builtin_amdgcn_mfma_f32_16x16x32_f16(kf1, qf1[mt], z, 0, 0, 0);
                float p0 = EXP2F(z[0]), p1 = EXP2F(z[1]);
                float p2 = EXP2F(z[2]), p3 = EXP2F(z[3]);
                rs[mt] += p0; rs[mt] += p1; rs[mt] += p2; rs[mt] += p3;
                fp16x2 ca = __builtin_amdgcn_cvt_pkrtz(p0, p1);
                fp16x2 cb = __builtin_amdgcn_cvt_pkrtz(p2, p3);
                if (nt < 2) {
                    pf0[mt][(nt & 1) * 4 + 0] = (_Float16)ca[0];
                    pf0[mt][(nt & 1) * 4 + 1] = (_Float16)ca[1];
                    pf0[mt][(nt & 1) * 4 + 2] = (_Float16)cb[0];
                    pf0[mt][(nt & 1) * 4 + 3] = (_Float16)cb[1];
                } else {
                    pf1[mt][(nt & 1) * 4 + 0] = (_Float16)ca[0];
                    pf1[mt][(nt & 1) * 4 + 1] = (_Float16)ca[1];
                    pf1[mt][(nt & 1) * 4 + 2] = (_Float16)cb[0];
                    pf1[mt][(nt & 1) * 4 + 3] = (_Float16)cb[1];
                }
            }
        }
        __builtin_amdgcn_s_setprio(0);

        // O^T += V^T·P^T
        __builtin_amdgcn_s_setprio(1);
        #pragma unroll
        for (int nt = 0; nt < 4; nt++) {
            half8 vf0 = *(half8*)&Vs[cur][(nt * 16 + l15) * 72 + quad * 8];
            half8 vf1 = *(half8*)&Vs[cur][(nt * 16 + l15) * 72 + 32 + quad * 8];
            #pragma unroll
            for (int mt = 0; mt < 2; mt++) {
                floatx4 a = acc[mt][nt];
                a = __builtin_amdgcn_mfma_f32_16x16x32_f16(vf0, pf0[mt], a, 0, 0, 0);
                a = __builtin_amdgcn_mfma_f32_16x16x32_f16(vf1, pf1[mt], a, 0, 0, 0);
                acc[mt][nt] = a;
            }
        }
        __builtin_amdgcn_s_setprio(0);

        if (it + 1 < NT) {
            *(half8*)&Ks[cur ^ 1][krP * 72 + kcol] = kreg;
            *(half8*)&Vs[cur ^ 1][kr  * 72 + kcol] = vreg;
        }
        cur ^= 1;
    }

    const size_t prow = (size_t)split * B_ * S_ + (size_t)b * S_ + q0;
    #pragma unroll
    for (int mt = 0; mt < 2; mt++) {
        float r = rs[mt];
        r += __shfl_xor(r, 16, 64);
        r += __shfl_xor(r, 32, 64);
        const float inv = 1.0f / r;
        const size_t orow = prow + wave * 32 + mt * 16 + l15;
        #pragma unroll
        for (int nt = 0; nt < 4; nt++) {
            half4v hv;
            #pragma unroll
            for (int i = 0; i < 4; i++)
                hv[i] = (_Float16)(acc[mt][nt][i] * inv);
            *(half4v*)(Oph + orow * DK + nt * 16 + quad * 4) = hv;
        }
        if (quad == 0)
            Lp[orow] = r;
    }
}

// ---------------------------------------------------------------------------
// Combine: O[r] = sum_s l_s * Ohat_s[r] / sum_s l_s.  16 rows x 16 lanes.
// ---------------------------------------------------------------------------
__global__ __launch_bounds__(256) void combine_kernel(
    const _Float16* __restrict__ Oph, const float* __restrict__ Lp,
    float* __restrict__ O)
{
    const int r  = blockIdx.x * 16 + (threadIdx.x >> 4);
    const int d4 = (threadIdx.x & 15) * 4;
    const int NR = B_ * S_;

    float lw[NSPLIT], lsum = 0.f;
    #pragma unroll
    for (int s = 0; s < NSPLIT; s++) {
        lw[s] = Lp[(size_t)s * NR + r];
        lsum += lw[s];
    }
    const float inv = 1.0f / lsum;

    float o[4] = {0.f, 0.f, 0.f, 0.f};
    #pragma unroll
    for (int s = 0; s < NSPLIT; s++) {
        half4v h = *(const half4v*)(Oph + ((size_t)s * NR + r) * DK + d4);
        const float w = lw[s];
        #pragma unroll
        for (int j = 0; j < 4; j++) o[j] += w * (float)h[j];
    }
    float4 out;
    out.x = o[0] * inv; out.y = o[1] * inv;
    out.z = o[2] * inv; out.w = o[3] * inv;
    *(float4*)(O + (size_t)r * DK + d4) = out;
}

// ---------------------------------------------------------------------------
extern "C" void kernel_launch(void* const* d_in, const int* in_sizes, int n_in,
                              void* d_out, int out_size, void* d_ws, size_t ws_size,
                              hipStream_t stream)
{
    const float* X  = (const float*)d_in[0];
    // cultural path (d_in[1], d_in[8..10]) cancels in softmax -> unused
    const float* WQ = (const float*)d_in[2];
    const float* bQ = (const float*)d_in[3];
    const float* WK = (const float*)d_in[4];
    const float* bK = (const float*)d_in[5];
    const float* WV = (const float*)d_in[6];
    const float* bV = (const float*)d_in[7];

    char* ws = (char*)d_ws;
    _Float16* Qh  = (_Float16*)ws;  ws += (size_t)B_ * S_ * DK * 2;   // 2 MiB
    _Float16* Kh  = (_Float16*)ws;  ws += (size_t)B_ * S_ * DK * 2;
    _Float16* Vt  = (_Float16*)ws;  ws += (size_t)B_ * S_ * DK * 2;
    _Float16* Wt  = (_Float16*)ws;  ws += (size_t)3 * 64 * DM * 2;    // 384 KiB
    _Float16* Oph = (_Float16*)ws;  ws += (size_t)NSPLIT * B_ * S_ * DK * 2; // 16 MiB
    float* Lp     = (float*)ws;

    wt_kernel<<<dim3(DM / 64, 3), 256, 0, stream>>>(WQ, WK, WV, Wt);

    proj_mfma_kernel<<<dim3((B_ * S_) / 64, 2), 256, 0, stream>>>(
        X, Wt, bQ, bK, bV, Qh, Kh, Vt);

    flash_mfma_kernel<<<dim3(S_ / QT, B_, NSPLIT), 512, 0, stream>>>(
        Qh, Kh, Vt, Oph, Lp);

    combine_kernel<<<dim3((B_ * S_) / 16), 256, 0, stream>>>(
        Oph, Lp, (float*)d_out);
}